// Round 3
// baseline (380.973 us; speedup 1.0000x reference)
//
#include <hip/hip_runtime.h>
#include <math.h>

#define N_NODES 100000
#define N_EDGES 1600000

// ================= CSR build (by dst) =================

__global__ void k_zero(int* __restrict__ cnt, int n) {
    int i = blockIdx.x * blockDim.x + threadIdx.x;
    if (i < n) cnt[i] = 0;
}

__global__ void k_count(const int* __restrict__ dst, int* __restrict__ cnt, int e) {
    int i = (blockIdx.x * blockDim.x + threadIdx.x) * 4;
    if (i + 3 < e) {
        int4 d4 = *(const int4*)(dst + i);
        atomicAdd(&cnt[d4.x], 1);
        atomicAdd(&cnt[d4.y], 1);
        atomicAdd(&cnt[d4.z], 1);
        atomicAdd(&cnt[d4.w], 1);
    } else {
        for (; i < e; ++i) atomicAdd(&cnt[dst[i]], 1);
    }
}

// scanA: per-block exclusive scan of 1024 ints (4/thread); block totals -> bsums.
// Also computes dinv = rsqrt(deg+1).
__global__ void k_scanA(const int* __restrict__ cnt, int* __restrict__ off,
                        int* __restrict__ bsums, float* __restrict__ dinv, int n) {
    __shared__ int sd[256];
    int t = threadIdx.x;
    int base = blockIdx.x * 1024 + t * 4;
    int e0 = (base + 0 < n) ? cnt[base + 0] : 0;
    int e1 = (base + 1 < n) ? cnt[base + 1] : 0;
    int e2 = (base + 2 < n) ? cnt[base + 2] : 0;
    int e3 = (base + 3 < n) ? cnt[base + 3] : 0;
    if (base + 0 < n) dinv[base + 0] = rsqrtf((float)e0 + 1.0f);
    if (base + 1 < n) dinv[base + 1] = rsqrtf((float)e1 + 1.0f);
    if (base + 2 < n) dinv[base + 2] = rsqrtf((float)e2 + 1.0f);
    if (base + 3 < n) dinv[base + 3] = rsqrtf((float)e3 + 1.0f);
    int s = e0 + e1 + e2 + e3;
    sd[t] = s;
    __syncthreads();
    for (int o = 1; o < 256; o <<= 1) {
        int v = (t >= o) ? sd[t - o] : 0;
        __syncthreads();
        sd[t] += v;
        __syncthreads();
    }
    int excl = sd[t] - s;
    if (base + 0 < n) off[base + 0] = excl;
    if (base + 1 < n) off[base + 1] = excl + e0;
    if (base + 2 < n) off[base + 2] = excl + e0 + e1;
    if (base + 3 < n) off[base + 3] = excl + e0 + e1 + e2;
    if (t == 0) bsums[blockIdx.x] = sd[255];
}

__global__ void k_scanB(int* __restrict__ bsums, int* __restrict__ off, int nb, int n) {
    __shared__ int sd[128];
    int t = threadIdx.x;
    int v = (t < nb) ? bsums[t] : 0;
    sd[t] = v;
    __syncthreads();
    for (int o = 1; o < 128; o <<= 1) {
        int u = (t >= o) ? sd[t - o] : 0;
        __syncthreads();
        sd[t] += u;
        __syncthreads();
    }
    if (t < nb) bsums[t] = sd[t] - v;
    if (t == 127) off[n] = sd[127];
}

__global__ void k_scanC(int* __restrict__ off, int* __restrict__ cursor,
                        const int* __restrict__ bsums, int n) {
    int i = blockIdx.x * blockDim.x + threadIdx.x;
    if (i < n) {
        int v = off[i] + bsums[i >> 10];
        off[i] = v;
        cursor[i] = v;
    }
}

__global__ void k_fill(const int* __restrict__ src, const int* __restrict__ dst,
                       int* __restrict__ cursor, int* __restrict__ csr, int e) {
    int i = (blockIdx.x * blockDim.x + threadIdx.x) * 4;
    if (i + 3 < e) {
        int4 s4 = *(const int4*)(src + i);
        int4 d4 = *(const int4*)(dst + i);
        csr[atomicAdd(&cursor[d4.x], 1)] = s4.x;
        csr[atomicAdd(&cursor[d4.y], 1)] = s4.y;
        csr[atomicAdd(&cursor[d4.z], 1)] = s4.z;
        csr[atomicAdd(&cursor[d4.w], 1)] = s4.w;
    } else {
        for (; i < e; ++i) csr[atomicAdd(&cursor[dst[i]], 1)] = src[i];
    }
}

// ======== Fused layer-1 front half: h2 = relu((A_hat X) W1 + b1) @ W2 ========
// 256 threads = 4 waves; 4 nodes per wave (16/block). lane = 16*q + c.
// Phase A (gather): per node, preload <=64 csr/dinv into lane regs (1 coalesced
//   load + 1 gather), then q-groups gather x rows as float4 (4 edges in flight
//   per instr), cross-q shfl_xor reduce -> agg row replicated in registers.
// Phase B (W1 from LDS): lane f accumulates over k via shfl broadcasts. relu.
// Phase C (W2 from LDS, padded): shfl broadcasts + cross-q reduce -> h2.

__global__ __launch_bounds__(256, 6) void k_agg1(
        const float* __restrict__ x, const int* __restrict__ off,
        const int* __restrict__ csr, const float* __restrict__ dinv,
        const float* __restrict__ W1, const float* __restrict__ W2,
        const float* __restrict__ b1, float* __restrict__ h2, int n) {
    __shared__ float W1s[64 * 64];
    __shared__ float W2s[64 * 17];  // padded: kills 4-way bank conflict in phase C
    int tid = threadIdx.x;
    {
        const float4* W14 = (const float4*)W1;
        float4* W1s4 = (float4*)W1s;
#pragma unroll
        for (int i = 0; i < 4; ++i) W1s4[tid + 256 * i] = W14[tid + 256 * i];
        for (int i = tid; i < 64 * 16; i += 256) {
            int k = i >> 4, cc = i & 15;
            W2s[k * 17 + cc] = W2[i];
        }
    }
    __syncthreads();  // only barrier in the kernel

    int w = tid >> 6;
    int lane = tid & 63;
    int q = lane >> 4;
    int c = lane & 15;
    int f = lane;
    float b1f = b1[f];
    const float4* x4 = (const float4*)x;

    int base = blockIdx.x * 16 + w * 4;
#pragma unroll 1
    for (int nn = 0; nn < 4; ++nn) {
        int d = base + nn;
        if (d >= n) break;
        float dd = dinv[d];
        // self-loop term (only q==0 contributes; merged at reduce)
        float4 selfv = x4[(size_t)d * 16 + c];
        float ax, ay, az, aw;
        if (q == 0) { ax = selfv.x * dd; ay = selfv.y * dd; az = selfv.z * dd; aw = selfv.w * dd; }
        else        { ax = 0.f; ay = 0.f; az = 0.f; aw = 0.f; }
        int jb = off[d], je = off[d + 1];
        for (int cs = jb; cs < je; cs += 64) {
            int rem = je - cs; if (rem > 64) rem = 64;
            int myS = 0; float myW = 0.f;
            if (lane < rem) { myS = csr[cs + lane]; myW = dinv[myS]; }
            int rounds = (rem + 3) >> 2;
            int r = 0;
            for (; r + 1 < rounds; r += 2) {
                int t0 = r * 4 + q, t1 = t0 + 4;
                int   s0 = __shfl(myS, t0); float w0 = __shfl(myW, t0);
                int   s1 = __shfl(myS, t1); float w1 = __shfl(myW, t1);
                float4 v0 = x4[(size_t)s0 * 16 + c];
                float4 v1 = x4[(size_t)s1 * 16 + c];
                ax = fmaf(v0.x, w0, ax); ay = fmaf(v0.y, w0, ay);
                az = fmaf(v0.z, w0, az); aw = fmaf(v0.w, w0, aw);
                ax = fmaf(v1.x, w1, ax); ay = fmaf(v1.y, w1, ay);
                az = fmaf(v1.z, w1, az); aw = fmaf(v1.w, w1, aw);
            }
            if (r < rounds) {
                int t0 = r * 4 + q;
                int   s0 = __shfl(myS, t0); float w0 = __shfl(myW, t0);
                float4 v0 = x4[(size_t)s0 * 16 + c];
                ax = fmaf(v0.x, w0, ax); ay = fmaf(v0.y, w0, ay);
                az = fmaf(v0.z, w0, az); aw = fmaf(v0.w, w0, aw);
            }
        }
        // cross-q reduce: every lane ends with agg for features c*4..c*4+3
        ax += __shfl_xor(ax, 16); ax += __shfl_xor(ax, 32);
        ay += __shfl_xor(ay, 16); ay += __shfl_xor(ay, 32);
        az += __shfl_xor(az, 16); az += __shfl_xor(az, 32);
        aw += __shfl_xor(aw, 16); aw += __shfl_xor(aw, 32);
        ax *= dd; ay *= dd; az *= dd; aw *= dd;
        // Phase B: out1[f] = b1[f] + sum_k agg[k]*W1[k][f]; relu
        float accB = b1f;
#pragma unroll
        for (int k4 = 0; k4 < 16; ++k4) {
            float vx = __shfl(ax, k4);
            float vy = __shfl(ay, k4);
            float vz = __shfl(az, k4);
            float vw = __shfl(aw, k4);
            accB = fmaf(vx, W1s[(k4 * 4 + 0) * 64 + f], accB);
            accB = fmaf(vy, W1s[(k4 * 4 + 1) * 64 + f], accB);
            accB = fmaf(vz, W1s[(k4 * 4 + 2) * 64 + f], accB);
            accB = fmaf(vw, W1s[(k4 * 4 + 3) * 64 + f], accB);
        }
        float vv = fmaxf(accB, 0.f);
        // Phase C: h2[d][c] = sum_k vv_k * W2[k][c]
        float p = 0.f;
#pragma unroll
        for (int kk = 0; kk < 16; ++kk) {
            int k = q * 16 + kk;
            float vk = __shfl(vv, k);
            p = fmaf(vk, W2s[k * 17 + c], p);
        }
        p += __shfl_xor(p, 16);
        p += __shfl_xor(p, 32);
        if (q == 0) h2[(size_t)d * 16 + c] = p;
    }
}

// ======== Layer-2 aggregation fused with b2 + log_softmax ========
// 4 waves/block, 1 node/wave; lane = 16*q + c. csr/dinv preloaded + shfl.

__global__ __launch_bounds__(256, 8) void k_agg2_lsm(
        const float* __restrict__ h2, const int* __restrict__ off,
        const int* __restrict__ csr, const float* __restrict__ dinv,
        const float* __restrict__ b2, float* __restrict__ y, int n) {
    int tid = threadIdx.x;
    int w = tid >> 6, lane = tid & 63, q = lane >> 4, c = lane & 15;
    int d = blockIdx.x * 4 + w;
    if (d >= n) return;
    float dd = dinv[d];
    float acc0 = (q == 0) ? h2[(size_t)d * 16 + c] * dd : 0.f;  // self-loop
    float acc1 = 0.f;
    int jb = off[d], je = off[d + 1];
    for (int cs = jb; cs < je; cs += 64) {
        int rem = je - cs; if (rem > 64) rem = 64;
        int myS = 0; float myW = 0.f;
        if (lane < rem) { myS = csr[cs + lane]; myW = dinv[myS]; }
        int rounds = (rem + 3) >> 2;
        int r = 0;
        for (; r + 1 < rounds; r += 2) {
            int t0 = r * 4 + q, t1 = t0 + 4;
            int s0 = __shfl(myS, t0); float w0 = __shfl(myW, t0);
            int s1 = __shfl(myS, t1); float w1 = __shfl(myW, t1);
            acc0 = fmaf(h2[(size_t)s0 * 16 + c], w0, acc0);
            acc1 = fmaf(h2[(size_t)s1 * 16 + c], w1, acc1);
        }
        if (r < rounds) {
            int t0 = r * 4 + q;
            int s0 = __shfl(myS, t0); float w0 = __shfl(myW, t0);
            acc0 = fmaf(h2[(size_t)s0 * 16 + c], w0, acc0);
        }
    }
    float acc = acc0 + acc1;
    acc += __shfl_xor(acc, 16);
    acc += __shfl_xor(acc, 32);
    float v = acc * dd + b2[c];
    float m = v;
#pragma unroll
    for (int o = 1; o < 16; o <<= 1) m = fmaxf(m, __shfl_xor(m, o));
    float ssum = expf(v - m);
#pragma unroll
    for (int o = 1; o < 16; o <<= 1) ssum += __shfl_xor(ssum, o);
    float r2 = v - (logf(ssum) + m);
    if (q == 0) y[(size_t)d * 16 + c] = r2;
}

// ================= launcher =================

extern "C" void kernel_launch(void* const* d_in, const int* in_sizes, int n_in,
                              void* d_out, int out_size, void* d_ws, size_t ws_size,
                              hipStream_t stream) {
    const float* x  = (const float*)d_in[0];
    const int*   ei = (const int*)d_in[1];          // [2, E] row-major
    const float* W1 = (const float*)d_in[2];
    const float* b1 = (const float*)d_in[3];
    const float* W2 = (const float*)d_in[4];
    const float* b2 = (const float*)d_in[5];
    float* y = (float*)d_out;

    const int n = N_NODES;
    const int e = N_EDGES;
    const int* src = ei;
    const int* dst = ei + e;

    // workspace layout (4-byte units); total ~10 MB
    float* ws = (float*)d_ws;
    int*   cnt    = (int*)ws;                       // n
    float* dinv   = ws + 102400;                    // n
    int*   off    = (int*)(ws + 204800);            // n+1
    int*   cursor = (int*)(ws + 307200);            // n
    int*   bsums  = (int*)(ws + 409600);            // <=1024
    int*   csr    = (int*)(ws + 410624);            // e
    float* h2     = (float*)(csr + e);              // n*16

    const int nb = (n + 1023) / 1024;               // 98 scan blocks (<=128)

    k_zero <<<(n + 255) / 256, 256, 0, stream>>>(cnt, n);
    k_count<<<(e / 4 + 255) / 256, 256, 0, stream>>>(dst, cnt, e);
    k_scanA<<<nb, 256, 0, stream>>>(cnt, off, bsums, dinv, n);
    k_scanB<<<1, 128, 0, stream>>>(bsums, off, nb, n);
    k_scanC<<<(n + 255) / 256, 256, 0, stream>>>(off, cursor, bsums, n);
    k_fill <<<(e / 4 + 255) / 256, 256, 0, stream>>>(src, dst, cursor, csr, e);

    k_agg1    <<<(n + 15) / 16, 256, 0, stream>>>(x, off, csr, dinv, W1, W2, b1, h2, n);
    k_agg2_lsm<<<(n + 3) / 4, 256, 0, stream>>>(h2, off, csr, dinv, b2, y, n);
}